// Round 2
// baseline (730.686 us; speedup 1.0000x reference)
//
#include <hip/hip_runtime.h>
#include <hip/hip_bf16.h>
#include <math.h>

#define VF 59
#define HF 128
#define BB 2048
#define TT 96
#define MR 16              // batch rows per block (one MFMA M-tile)
#define NBLK (BB / MR)     // 128 blocks
#define NTH 512            // 8 waves

typedef __attribute__((ext_vector_type(8))) short short8;   // 8 x bf16 (4 VGPR)
typedef __attribute__((ext_vector_type(4))) float f32x4;    // MFMA accumulator

#define MFMA(a, b, c) __builtin_amdgcn_mfma_f32_16x16x32_bf16((a), (b), (c), 0, 0, 0)

// ---------------- ws layout ----------------
#define WF_INV   0          // 96: 1/(sum(mask_t)+1e-5)  (finalized in prep_pack)
#define WF_ACC   96         // 96: atomic accumulators (zeroed in prep_zero)
#define WF_DWDX  192        // 59: diag(Wdx)
#define WF_END   256
// bf16 (ushort) region — B-operand fragments:
//   frag[(tile*KS + ks)*64 + lane] = 8 bf16: W[tile*16+(lane&15)][ks*32+(lane>>4)*8 + j]
#define U_B1  (WF_END * 2)        // Wdh  [128][59]  tiles=8,  KS=2 -> 8192
#define U_B2  (U_B1 + 8192)       // Wh   [59][128]  tiles=4,  KS=4 -> 8192
#define U_B3  (U_B2 + 8192)       // Wf   [59][59]   tiles=4,  KS=2 -> 4096 (diag zeroed)
#define U_B4  (U_B3 + 4096)       // Wc   [59][118]  tiles=4,  KS=4 -> 8192
#define U_B5  (U_B4 + 8192)       // Wih  [384][118] tiles=24, KS=4 -> 49152
#define U_B6  (U_B5 + 49152)      // Whh  [384][128] tiles=24, KS=4 -> 49152

#define LOSS_IDX (BB * TT * VF)
#define OFF_HID  (BB * TT * VF + 1)

// ---------------- LDS layout (fragment-layout A-buffers) ----------------
// ushort offsets; frag buffers: idx = (ks*64 + (colq)*16 + row)*8 + (col&7)
#define S_AD    0                 // d      K=64  -> 1024
#define S_AH    1024              // h_dec  K=128 -> 2048  (ends 3072)
#define S_AGM0  3072              // [gx|m] K=128 -> 2048  (parity double buffer)
#define S_AGM1  5120              //                       (ends 7168)
#define S_AIM0  7168              // [ximp|m] K=128 -> 2048 (parity)
#define S_AIM1  9216              //                       (ends 11264)
#define S_XR    11264             // x_r scratch, 4 X-waves x K=64 -> 4096 (ends 15360)
#define S_WH    15360             // Wh B-fragments copy: 8192 (ends 23552)
// float offsets (= ushort idx / 2)
#define F_SX    11776             // x_t [16][60] -> 960
#define F_SM    12736             // m_t [16][60] -> 960
#define F_RED   13696             // 8 loss partials
#define F_IDT   13704             // 96: 1/(sum mask_t + eps)
#define F_TOT   13800             // 55200 B LDS

__device__ __forceinline__ ushort f2bf(float f) {
    __hip_bfloat16 h = __float2bfloat16(f);
    return *reinterpret_cast<ushort*>(&h);
}
__device__ __forceinline__ float sigm(float v) { return 1.f / (1.f + __expf(-v)); }
__device__ __forceinline__ float tanh_f(float v) {
    float c = fminf(fmaxf(v, -15.f), 15.f);
    float e = __expf(-2.f * c);
    return (1.f - e) / (1.f + e);
}
// ushort index of element (row, col) inside a fragment-layout A-buffer
__device__ __forceinline__ int fragIdx(int row, int col) {
    return ((col >> 5) * 64 + ((col >> 3) & 3) * 16 + row) * 8 + (col & 7);
}

// Raw barrier: LDS-only wait (global loads/stores stay in flight).
__device__ __forceinline__ void block_sync() {
    asm volatile("s_waitcnt lgkmcnt(0)" ::: "memory");
    __builtin_amdgcn_s_barrier();
    asm volatile("" ::: "memory");
}

// ---------------- prep 1: zero accumulators ----------------
__global__ __launch_bounds__(128) void prep_zero(float* __restrict__ ws, float* __restrict__ loss_ptr) {
    int tid = threadIdx.x;
    if (tid < TT) ws[WF_ACC + tid] = 0.f;
    if (tid == 96) loss_ptr[0] = 0.f;
}

// ---------------- prep 2: streaming per-t mask sums (round-0 proven version) ----------------
__global__ __launch_bounds__(256) void prep_acc(const float* __restrict__ mask, float* __restrict__ ws) {
    __shared__ float acc[TT];
    int tid = threadIdx.x;
    if (tid < TT) acc[tid] = 0.f;
    __syncthreads();
    #pragma unroll
    for (int rr = 0; rr < 2; ++rr) {
        int row = blockIdx.x * 512 + rr * 256 + tid;    // row = b*TT + t, rows = BB*TT
        const float* p = mask + (size_t)row * VF;
        float s = 0.f;
        #pragma unroll
        for (int v = 0; v < VF; ++v) s += p[v];
        atomicAdd(&acc[row % TT], s);
    }
    __syncthreads();
    if (tid < TT) atomicAdd(&ws[WF_ACC + tid], acc[tid]);
}

// ---------------- prep 3: pack B fragments + finalize ----------------
__device__ void packB(const float* __restrict__ W, int G, int K, int tiles, int KS,
                      int zdiag, ushort* __restrict__ dst, int gtid, int gstride) {
    int total = tiles * KS * 512;
    for (int idx = gtid; idx < total; idx += gstride) {
        int j  = idx & 7;
        int l  = (idx >> 3) & 63;
        int tk = idx >> 9;
        int ks = tk % KS;
        int tile = tk / KS;
        int g = tile * 16 + (l & 15);
        int k = ks * 32 + ((l >> 4) << 3) + j;
        float v = 0.f;
        if (g < G && k < K) v = W[g * K + k];
        if (zdiag && g == k) v = 0.f;
        dst[idx] = f2bf(v);
    }
}

__global__ __launch_bounds__(256) void prep_pack(
    const float* __restrict__ Wdh, const float* __restrict__ Wdx,
    const float* __restrict__ Wh,  const float* __restrict__ Wf,
    const float* __restrict__ Wc,  const float* __restrict__ Wih,
    const float* __restrict__ Whh, float* __restrict__ ws)
{
    int blk = blockIdx.x, tid = threadIdx.x;
    if (blk == 64) {
        if (tid < TT) ws[WF_INV + tid] = 1.f / (ws[WF_ACC + tid] + 1e-5f);
        if (tid < VF) ws[WF_DWDX + tid] = Wdx[tid * VF + tid];
        return;
    }
    ushort* wsu = (ushort*)ws;
    int gtid = blk * 256 + tid;
    int gstride = 64 * 256;
    packB(Wdh, HF,     VF,     8,  2, 0, wsu + U_B1, gtid, gstride);
    packB(Wh,  VF,     HF,     4,  4, 0, wsu + U_B2, gtid, gstride);
    packB(Wf,  VF,     VF,     4,  2, 1, wsu + U_B3, gtid, gstride);
    packB(Wc,  VF,     2*VF,   4,  4, 0, wsu + U_B4, gtid, gstride);
    packB(Wih, 3*HF,   2*VF,   24, 4, 0, wsu + U_B5, gtid, gstride);
    packB(Whh, 3*HF,   HF,     24, 4, 0, wsu + U_B6, gtid, gstride);
}

// ---------------- main recurrence ----------------
// 2-phase schedule:
//   A: all waves: gh GEMM (accs ride to C).
//      X-waves (0-3): FULL x_h (4 tiles, Wh frags from LDS) -> x_r -> in-wave
//        scratch roundtrip -> xu GEMM + beta GEMM + combine/loss/x_imp (own tile).
//      L-waves (4-7): commit d(t+1)+gx(t+1) (from regs loaded a step ago);
//        issue t+2 prefetch.
//   C: all waves: gi GEMM + gamma(t+1) GEMM + gates + h_decay(t+1) -> S_AH.
//      L-waves tail: commit x/m(t+1); rotate prefetch regs.
__global__ __launch_bounds__(NTH, 2) void rits_main(
    const float* __restrict__ x, const float* __restrict__ mask, const float* __restrict__ deltas,
    const float* __restrict__ bdh, const float* __restrict__ bdx, const float* __restrict__ bh,
    const float* __restrict__ bf,  const float* __restrict__ bc,
    const float* __restrict__ bih, const float* __restrict__ bhh,
    const float* __restrict__ ws, float* __restrict__ out)
{
    __shared__ __align__(16) float smf[F_TOT];
    ushort* smu = (ushort*)smf;

    const int tid  = threadIdx.x;
    const int lane = tid & 63;
    const int w    = tid >> 6;         // wave 0..7
    const int ln15 = lane & 15;
    const int quad = lane >> 4;
    const int b0   = blockIdx.x * MR;

    const ushort* wsu = (const ushort*)ws;
    const short8* B1 = (const short8*)(wsu + U_B1);
    const short8* B3 = (const short8*)(wsu + U_B3);
    const short8* B4 = (const short8*)(wsu + U_B4);
    const short8* B5 = (const short8*)(wsu + U_B5);
    const short8* B6 = (const short8*)(wsu + U_B6);

    // ---- hoist weight fragments into registers (t-invariant) ----
    short8 wB1[2];
    #pragma unroll
    for (int i = 0; i < 2; ++i) wB1[i] = B1[(w * 2 + i) * 64 + lane];
    short8 wB5[12], wB6[12];
    #pragma unroll
    for (int tt = 0; tt < 3; ++tt)
        #pragma unroll
        for (int ks = 0; ks < 4; ++ks) {
            wB5[tt * 4 + ks] = B5[((w + tt * 8) * 4 + ks) * 64 + lane];
            wB6[tt * 4 + ks] = B6[((w + tt * 8) * 4 + ks) * 64 + lane];
        }
    // X-wave-only weights (Wf / Wc slices for own v-tile)
    short8 wB3[2], wB4[4];
    if (w < 4) {
        #pragma unroll
        for (int i = 0; i < 2; ++i) wB3[i] = B3[(w * 2 + i) * 64 + lane];
        #pragma unroll
        for (int ks = 0; ks < 4; ++ks) wB4[ks] = B4[(w * 4 + ks) * 64 + lane];
    }

    // hoisted per-thread bias constants
    const int jH = w * 16 + ln15;
    const float c_bdh = bdh[jH];
    const float c_br  = bih[jH]       + bhh[jH];
    const float c_bz  = bih[jH + 128] + bhh[jH + 128];
    const float c_bin = bih[jH + 256];
    const float c_bhn = bhh[jH + 256];
    const int vC = (w < 4 ? w : w - 4) * 16 + ln15;
    const float c_bf = (w < 4 && vC < VF) ? bf[vC] : 0.f;
    const float c_bc = (w < 4 && vC < VF) ? bc[vC] : 0.f;
    float c_bh4[4];
    #pragma unroll
    for (int tile = 0; tile < 4; ++tile) {
        int col = tile * 16 + ln15;
        c_bh4[tile] = (col < VF) ? bh[col] : 0.f;
    }

    // ---- loader mapping (waves 4-7): row lr, col lc + 16k ----
    const int q  = tid & 255;
    const int lr = q >> 4;
    const int lc = q & 15;
    const size_t rowbase = (size_t)(b0 + lr) * (TT * VF);
    const float* px = x + rowbase;
    const float* pm = mask + rowbase;
    const float* pd = deltas + rowbase;
    float wdx4[4], bdx4[4];
    #pragma unroll
    for (int k = 0; k < 4; ++k) {
        int v = lc + 16 * k;
        wdx4[k] = (v < VF) ? ws[WF_DWDX + v] : 0.f;
        bdx4[k] = (v < VF) ? bdx[v] : 0.f;
    }

    float hreg[4] = {0.f, 0.f, 0.f, 0.f};   // holds h_decay(t) at top of step t

    // zero LDS (frag pads must be zero; S_AH=0 == h_decay(0))
    for (int i = tid; i < F_TOT; i += NTH) smf[i] = 0.f;
    __syncthreads();

    // stage Wh fragments into LDS (read every step by X-waves)
    {
        const int4* src = (const int4*)(wsu + U_B2);
        int4* dst = (int4*)(smu + S_WH);
        for (int i = tid; i < 1024; i += NTH) dst[i] = src[i];
    }
    if (tid < TT) smf[F_IDT + tid] = ws[WF_INV + tid];

    // t=0 inputs (L-waves) + load t=1 into commit regs
    float cxv[4], cmv[4], cdv[4];
    if (w >= 4) {
        #pragma unroll
        for (int k = 0; k < 4; ++k) {
            int v = lc + 16 * k;
            if (v < VF) {
                float xv = px[v], mv = pm[v], dv = pd[v];
                smf[F_SX + lr * 60 + v] = xv;
                smf[F_SM + lr * 60 + v] = mv;
                ushort mb = f2bf(mv);
                smu[S_AGM0 + fragIdx(lr, 59 + v)] = mb;
                smu[S_AIM0 + fragIdx(lr, 59 + v)] = mb;
                float gx = __expf(-fmaxf(fmaf(dv, wdx4[k], bdx4[k]), 0.f));
                smu[S_AGM0 + fragIdx(lr, v)] = f2bf(gx);
                // t=1 prefetch into commit regs
                cxv[k] = px[VF + v]; cmv[k] = pm[VF + v]; cdv[k] = pd[VF + v];
            }
        }
    }
    __syncthreads();

    float loss_acc = 0.f;

    for (int t = 0; t < TT; ++t) {
        const int p = t & 1;
        const int aimC = S_AIM0 + p * 2048;            // current-step [ximp|m]
        // ---- issue t+2 prefetch (L-waves) ----
        float nxv[4], nmv[4], ndv[4];
        if (w >= 4 && t + 2 < TT) {
            const size_t toff = (size_t)(t + 2) * VF;
            #pragma unroll
            for (int k = 0; k < 4; ++k) {
                int v = lc + 16 * k;
                if (v < VF) { nxv[k] = px[toff + v]; nmv[k] = pm[toff + v]; ndv[k] = pd[toff + v]; }
            }
        }

        // ================= Phase A =================
        short8 ah[4];
        #pragma unroll
        for (int ks = 0; ks < 4; ++ks)
            ah[ks] = *(const short8*)(smu + S_AH + (ks * 64 + lane) * 8);
        f32x4 gHa[3];
        #pragma unroll
        for (int tt = 0; tt < 3; ++tt) gHa[tt] = (f32x4){0.f, 0.f, 0.f, 0.f};
        #pragma unroll
        for (int tt = 0; tt < 3; ++tt)
            #pragma unroll
            for (int ks = 0; ks < 4; ++ks) gHa[tt] = MFMA(ah[ks], wB6[tt * 4 + ks], gHa[tt]);

        if (w < 4) {
            // beta A-frags (issue early)
            const int agmC = S_AGM0 + p * 2048;
            short8 ag[4];
            #pragma unroll
            for (int ks = 0; ks < 4; ++ks)
                ag[ks] = *(const short8*)(smu + agmC + (ks * 64 + lane) * 8);
            // full x_h, tile by tile; write x_r to private scratch
            float xh_own[4], mm_own[4], xx_own[4];
            const int xrb = S_XR + w * 1024;
            #pragma unroll
            for (int tile = 0; tile < 4; ++tile) {
                short8 wh0 = *(const short8*)(smu + S_WH + ((tile * 4 + 0) * 64 + lane) * 8);
                short8 wh1 = *(const short8*)(smu + S_WH + ((tile * 4 + 1) * 64 + lane) * 8);
                short8 wh2 = *(const short8*)(smu + S_WH + ((tile * 4 + 2) * 64 + lane) * 8);
                short8 wh3 = *(const short8*)(smu + S_WH + ((tile * 4 + 3) * 64 + lane) * 8);
                f32x4 acc = {0.f, 0.f, 0.f, 0.f};
                acc = MFMA(ah[0], wh0, acc);
                acc = MFMA(ah[1], wh1, acc);
                acc = MFMA(ah[2], wh2, acc);
                acc = MFMA(ah[3], wh3, acc);
                int col = tile * 16 + ln15;
                if (col < VF) {
                    #pragma unroll
                    for (int i = 0; i < 4; ++i) {
                        int m = quad * 4 + i;
                        float xh = acc[i] + c_bh4[tile];
                        float mm = smf[F_SM + m * 60 + col];
                        float xx = smf[F_SX + m * 60 + col];
                        float xr = fmaf(mm, xx, (1.f - mm) * xh);
                        smu[xrb + fragIdx(m, col)] = f2bf(xr);
                        if (tile == w) { xh_own[i] = xh; mm_own[i] = mm; xx_own[i] = xx; }
                    }
                }
            }
            // in-wave roundtrip: drain writes, then read x_r fragments
            asm volatile("s_waitcnt lgkmcnt(0)" ::: "memory");
            __builtin_amdgcn_sched_barrier(0);
            short8 xr0 = *(const short8*)(smu + xrb + (0 * 64 + lane) * 8);
            short8 xr1 = *(const short8*)(smu + xrb + (1 * 64 + lane) * 8);
            f32x4 xua = {0.f, 0.f, 0.f, 0.f};
            xua = MFMA(xr0, wB3[0], xua);
            xua = MFMA(xr1, wB3[1], xua);
            f32x4 bacc = {0.f, 0.f, 0.f, 0.f};
            #pragma unroll
            for (int ks = 0; ks < 4; ++ks) bacc = MFMA(ag[ks], wB4[ks], bacc);
            // combine + loss + x_imp (own tile; xh/m/x already in regs)
            if (vC < VF) {
                const float idt = smf[F_IDT + t];
                #pragma unroll
                for (int i = 0; i < 4; ++i) {
                    int m = quad * 4 + i;
                    float xu   = xua[i] + c_bf;           // Wf diag zeroed at pack time
                    float beta = bacc[i] + c_bc;
                    float xc   = beta * xu + (1.f - beta) * xh_own[i];
                    float mm   = mm_own[i];
                    float xv   = xx_own[i];
                    loss_acc += fabsf(xv - xc) * mm * idt;
                    float xi = fmaf(mm, xv, (1.f - mm) * xc);
                    out[(size_t)(b0 + m) * (TT * VF) + (size_t)t * VF + vC] = xi;
                    smu[aimC + fragIdx(m, vC)] = f2bf(xi);
                }
            }
        } else if (t + 1 < TT) {
            // commit d(t+1) + gx(t+1) from regs loaded a full step ago
            const int agmN = S_AGM0 + ((t + 1) & 1) * 2048;
            #pragma unroll
            for (int k = 0; k < 4; ++k) {
                int v = lc + 16 * k;
                if (v < VF) {
                    smu[S_AD + fragIdx(lr, v)] = f2bf(cdv[k]);
                    float gx = __expf(-fmaxf(fmaf(cdv[k], wdx4[k], bdx4[k]), 0.f));
                    smu[agmN + fragIdx(lr, v)] = f2bf(gx);
                }
            }
        }
        block_sync();

        // ================= Phase C =================
        {
            short8 ai[4];
            #pragma unroll
            for (int ks = 0; ks < 4; ++ks)
                ai[ks] = *(const short8*)(smu + aimC + (ks * 64 + lane) * 8);
            f32x4 gI[3];
            #pragma unroll
            for (int tt = 0; tt < 3; ++tt) gI[tt] = (f32x4){0.f, 0.f, 0.f, 0.f};
            #pragma unroll
            for (int tt = 0; tt < 3; ++tt)
                #pragma unroll
                for (int ks = 0; ks < 4; ++ks) gI[tt] = MFMA(ai[ks], wB5[tt * 4 + ks], gI[tt]);
            float gdec[4] = {0.f, 0.f, 0.f, 0.f};
            if (t + 1 < TT) {
                short8 d0 = *(const short8*)(smu + S_AD + (0 * 64 + lane) * 8);
                short8 d1 = *(const short8*)(smu + S_AD + (1 * 64 + lane) * 8);
                f32x4 gacc = {0.f, 0.f, 0.f, 0.f};
                gacc = MFMA(d0, wB1[0], gacc);
                gacc = MFMA(d1, wB1[1], gacc);
                #pragma unroll
                for (int i = 0; i < 4; ++i)
                    gdec[i] = __expf(-fmaxf(gacc[i] + c_bdh, 0.f));
            }
            #pragma unroll
            for (int i = 0; i < 4; ++i) {
                int m = quad * 4 + i;
                float r_ = sigm(gI[0][i] + gHa[0][i] + c_br);
                float z_ = sigm(gI[1][i] + gHa[1][i] + c_bz);
                float hn = gHa[2][i] + c_bhn;
                float n_ = tanh_f(fmaf(r_, hn, gI[2][i] + c_bin));
                float hnew = fmaf(z_, hreg[i] - n_, n_);
                out[OFF_HID + (size_t)(b0 + m) * (TT * HF) + (size_t)t * HF + jH] = hnew;
                float hd = hnew * gdec[i];               // h_decay(t+1)
                hreg[i] = hd;
                if (t + 1 < TT) smu[S_AH + fragIdx(m, jH)] = f2bf(hd);
            }
        }
        // C tail: L-waves commit x/m(t+1), rotate prefetch regs
        if (w >= 4 && t + 1 < TT) {
            const int aimN = S_AIM0 + ((t + 1) & 1) * 2048;
            const int agmN = S_AGM0 + ((t + 1) & 1) * 2048;
            #pragma unroll
            for (int k = 0; k < 4; ++k) {
                int v = lc + 16 * k;
                if (v < VF) {
                    smf[F_SX + lr * 60 + v] = cxv[k];
                    smf[F_SM + lr * 60 + v] = cmv[k];
                    ushort mb = f2bf(cmv[k]);
                    smu[agmN + fragIdx(lr, 59 + v)] = mb;
                    smu[aimN + fragIdx(lr, 59 + v)] = mb;
                }
            }
            if (t + 2 < TT) {
                #pragma unroll
                for (int k = 0; k < 4; ++k) { cxv[k] = nxv[k]; cmv[k] = nmv[k]; cdv[k] = ndv[k]; }
            }
        }
        block_sync();
    }

    // ---- loss reduction ----
    __syncthreads();
    float vsum = loss_acc;
    for (int off = 32; off > 0; off >>= 1) vsum += __shfl_down(vsum, off);
    if (lane == 0) smf[F_RED + w] = vsum;
    __syncthreads();
    if (tid == 0) {
        float s = 0.f;
        #pragma unroll
        for (int i = 0; i < 8; ++i) s += smf[F_RED + i];
        atomicAdd(out + LOSS_IDX, s);
    }
}

extern "C" void kernel_launch(void* const* d_in, const int* in_sizes, int n_in,
                              void* d_out, int out_size, void* d_ws, size_t ws_size,
                              hipStream_t stream) {
    const float* x      = (const float*)d_in[0];
    const float* mask   = (const float*)d_in[1];
    const float* deltas = (const float*)d_in[2];
    const float* Wdh    = (const float*)d_in[3];
    const float* bdh    = (const float*)d_in[4];
    const float* Wdx    = (const float*)d_in[5];
    const float* bdx    = (const float*)d_in[6];
    const float* Wh     = (const float*)d_in[7];
    const float* bh     = (const float*)d_in[8];
    const float* Wf     = (const float*)d_in[9];
    const float* bf     = (const float*)d_in[10];
    const float* Wc     = (const float*)d_in[11];
    const float* bc     = (const float*)d_in[12];
    const float* Wih    = (const float*)d_in[13];
    const float* Whh    = (const float*)d_in[14];
    const float* bih    = (const float*)d_in[15];
    const float* bhh    = (const float*)d_in[16];
    float* out = (float*)d_out;
    float* ws  = (float*)d_ws;

    prep_zero<<<1, 128, 0, stream>>>(ws, out + LOSS_IDX);
    prep_acc<<<384, 256, 0, stream>>>(mask, ws);
    prep_pack<<<65, 256, 0, stream>>>(Wdh, Wdx, Wh, Wf, Wc, Wih, Whh, ws);
    rits_main<<<NBLK, NTH, 0, stream>>>(x, mask, deltas, bdh, bdx, bh, bf, bc,
                                        bih, bhh, ws, out);
}

// Round 3
// 527.190 us; speedup vs baseline: 1.3860x; 1.3860x over previous
//
#include <hip/hip_runtime.h>
#include <hip/hip_bf16.h>
#include <math.h>

#define VF 59
#define HF 128
#define BB 2048
#define TT 96
#define MR 16              // batch rows per block (one MFMA M-tile)
#define NBLK (BB / MR)     // 128 blocks
#define NTH 512            // 8 waves

typedef __attribute__((ext_vector_type(8))) short short8;   // 8 x bf16 (4 VGPR)
typedef __attribute__((ext_vector_type(4))) float f32x4;    // MFMA accumulator

#define MFMA(a, b, c) __builtin_amdgcn_mfma_f32_16x16x32_bf16((a), (b), (c), 0, 0, 0)

// ---------------- ws layout ----------------
#define WF_INV   0          // 96: 1/(sum(mask_t)+1e-5)  (finalized in prep_pack)
#define WF_ACC   96         // 96: atomic accumulators (zeroed in prep_zero)
#define WF_DWDX  192        // 59: diag(Wdx)
#define WF_END   256
// bf16 (ushort) region — B-operand fragments:
//   frag[(tile*KS + ks)*64 + lane] = 8 bf16: W[tile*16+(lane&15)][ks*32+(lane>>4)*8 + j]
#define U_B1  (WF_END * 2)        // Wdh  [128][59]  tiles=8,  KS=2 -> 8192
#define U_B2  (U_B1 + 8192)       // Wh   [59][128]  tiles=4,  KS=4 -> 8192
#define U_B3  (U_B2 + 8192)       // Wf   [59][59]   tiles=4,  KS=2 -> 4096 (diag zeroed)
#define U_B4  (U_B3 + 4096)       // Wc   [59][118]  tiles=4,  KS=4 -> 8192
#define U_B5  (U_B4 + 8192)       // Wih  [384][118] tiles=24, KS=4 -> 49152
#define U_B6  (U_B5 + 49152)      // Whh  [384][128] tiles=24, KS=4 -> 49152

#define LOSS_IDX (BB * TT * VF)
#define OFF_HID  (BB * TT * VF + 1)

// ---------------- LDS layout ----------------
// A-operand buffers in FRAGMENT layout: element (row m, col k) lives at
//   fragIdx(m,k) = ((k>>5)*64 + ((k>>3)&3)*16 + m)*8 + (k&7)   (ushorts)
// so a wave's ds_read_b128 at (ks*64+lane)*8 is lane-linear (16 B stride,
// 2 lanes/bank = conflict-free), replacing the ~8-way-conflicted row-major
// strided reads of the previous layout.
#define S_AD    0                 // d        K=64  -> 1024
#define S_AH    1024              // h_decay  K=128 -> 2048 (ends 3072)
#define S_AGM   3072              // [gx|m]   K=128 -> 2048 (ends 5120) single buffer
#define S_AIM0  5120              // [ximp|m] K=128 -> 2048 (parity double buffer)
#define S_AIM1  7168              //                        (ends 9216)
#define S_AXR   9216              // x_r      K=64  -> 1024 (ends 10240)
// float offsets (= ushort idx / 2); float region starts at ushort 10240
#define F_SX    5120              // x_t  [16][60] -> 960
#define F_SM    6080              // m_t  [16][60] -> 960
#define F_SB    7040              // beta [16][64] (swizzled col) -> 1024
#define F_RED   8064              // 8 loss partials
#define F_IDT   8072              // 96: 1/(sum mask_t + eps)
#define F_TOT   8168              // 32672 B LDS

__device__ __forceinline__ ushort f2bf(float f) {
    __hip_bfloat16 h = __float2bfloat16(f);
    return *reinterpret_cast<ushort*>(&h);
}
__device__ __forceinline__ float sigm(float v) { return 1.f / (1.f + __expf(-v)); }
__device__ __forceinline__ float tanh_f(float v) {
    float c = fminf(fmaxf(v, -15.f), 15.f);
    float e = __expf(-2.f * c);
    return (1.f - e) / (1.f + e);
}
// ushort index of element (row, col) inside a fragment-layout A-buffer
__device__ __forceinline__ int fragIdx(int row, int col) {
    return ((col >> 5) * 64 + ((col >> 3) & 3) * 16 + row) * 8 + (col & 7);
}
// beta exchange swizzle (both producer and consumer use it): rotate col by 4*m
// so the 4 quads of a wave land on disjoint bank groups (was 4-way conflict).
__device__ __forceinline__ int betaIdx(int m, int col) {
    return m * 64 + ((col + 4 * m) & 63);
}

// Raw barrier: LDS-only wait (global loads/stores stay in flight).
__device__ __forceinline__ void block_sync() {
    asm volatile("s_waitcnt lgkmcnt(0)" ::: "memory");
    __builtin_amdgcn_s_barrier();
    asm volatile("" ::: "memory");
}

// ---------------- prep 1: zero accumulators ----------------
__global__ __launch_bounds__(128) void prep_zero(float* __restrict__ ws, float* __restrict__ loss_ptr) {
    int tid = threadIdx.x;
    if (tid < TT) ws[WF_ACC + tid] = 0.f;
    if (tid == 96) loss_ptr[0] = 0.f;
}

// ---------------- prep 2: per-t mask sums, coalesced via LDS staging ----------------
// 1536 blocks x 128 rows: float4-coalesced global reads (exact: 1888 float4/block),
// per-row LDS sums (stride 59 = odd -> conflict-free), two-level atomics.
#define PA_R 128
__global__ __launch_bounds__(256) void prep_acc(const float* __restrict__ mask, float* __restrict__ ws) {
    __shared__ float buf[PA_R * VF];     // 30208 B
    __shared__ float acc[TT];
    int tid = threadIdx.x;
    if (tid < TT) acc[tid] = 0.f;
    const float4* src = (const float4*)(mask + (size_t)blockIdx.x * (PA_R * VF));
    float4* dst = (float4*)buf;
    #pragma unroll
    for (int i = 0; i < 8; ++i) {
        int idx = tid + i * 256;
        if (idx < PA_R * VF / 4) dst[idx] = src[idx];
    }
    __syncthreads();
    if (tid < PA_R) {
        float s = 0.f;
        #pragma unroll
        for (int v = 0; v < VF; ++v) s += buf[tid * VF + v];
        int t = (blockIdx.x * PA_R + tid) % TT;
        atomicAdd(&acc[t], s);
    }
    __syncthreads();
    if (tid < TT) atomicAdd(&ws[WF_ACC + tid], acc[tid]);
}

// ---------------- prep 3: pack B fragments + finalize ----------------
__device__ void packB(const float* __restrict__ W, int G, int K, int tiles, int KS,
                      int zdiag, ushort* __restrict__ dst, int gtid, int gstride) {
    int total = tiles * KS * 512;
    for (int idx = gtid; idx < total; idx += gstride) {
        int j  = idx & 7;
        int l  = (idx >> 3) & 63;
        int tk = idx >> 9;
        int ks = tk % KS;
        int tile = tk / KS;
        int g = tile * 16 + (l & 15);
        int k = ks * 32 + ((l >> 4) << 3) + j;
        float v = 0.f;
        if (g < G && k < K) v = W[g * K + k];
        if (zdiag && g == k) v = 0.f;
        dst[idx] = f2bf(v);
    }
}

__global__ __launch_bounds__(256) void prep_pack(
    const float* __restrict__ Wdh, const float* __restrict__ Wdx,
    const float* __restrict__ Wh,  const float* __restrict__ Wf,
    const float* __restrict__ Wc,  const float* __restrict__ Wih,
    const float* __restrict__ Whh, float* __restrict__ ws)
{
    int blk = blockIdx.x, tid = threadIdx.x;
    if (blk == 64) {
        if (tid < TT) ws[WF_INV + tid] = 1.f / (ws[WF_ACC + tid] + 1e-5f);
        if (tid < VF) ws[WF_DWDX + tid] = Wdx[tid * VF + tid];
        return;
    }
    ushort* wsu = (ushort*)ws;
    int gtid = blk * 256 + tid;
    int gstride = 64 * 256;
    packB(Wdh, HF,     VF,     8,  2, 0, wsu + U_B1, gtid, gstride);
    packB(Wh,  VF,     HF,     4,  4, 0, wsu + U_B2, gtid, gstride);
    packB(Wf,  VF,     VF,     4,  2, 1, wsu + U_B3, gtid, gstride);
    packB(Wc,  VF,     2*VF,   4,  4, 0, wsu + U_B4, gtid, gstride);
    packB(Wih, 3*HF,   2*VF,   24, 4, 0, wsu + U_B5, gtid, gstride);
    packB(Whh, 3*HF,   HF,     24, 4, 0, wsu + U_B6, gtid, gstride);
}

// ---------------- main recurrence ----------------
// 3-phase schedule (proven R1 structure; 3 barriers = dataflow floor for the
// 3 cross-wave exchanges h / x_r / x_imp):
//   A: gamma-free: all waves gh GEMM (accs ride to C); x_h GEMM (w0-3) |
//      beta GEMM (w4-7); x_r written to S_AXR.
//   B: xu GEMM + combine/loss/x_imp (w0-3) | commit d(t+1)->S_AD,S_AGM (w4-7)
//   C: gi GEMM + gamma(t+1) GEMM + gates; h_decay(t+1) -> S_AH;
//      tail: w4-7 commit x/m(t+1).
__global__ __launch_bounds__(NTH, 2) void rits_main(
    const float* __restrict__ x, const float* __restrict__ mask, const float* __restrict__ deltas,
    const float* __restrict__ bdh, const float* __restrict__ bdx, const float* __restrict__ bh,
    const float* __restrict__ bf,  const float* __restrict__ bc,
    const float* __restrict__ bih, const float* __restrict__ bhh,
    const float* __restrict__ ws, float* __restrict__ out)
{
    __shared__ __align__(16) float smf[F_TOT];
    ushort* smu = (ushort*)smf;

    const int tid  = threadIdx.x;
    const int lane = tid & 63;
    const int w    = tid >> 6;         // wave 0..7
    const int ln15 = lane & 15;
    const int quad = lane >> 4;
    const int b0   = blockIdx.x * MR;

    const ushort* wsu = (const ushort*)ws;
    const short8* B1 = (const short8*)(wsu + U_B1);
    const short8* B2 = (const short8*)(wsu + U_B2);
    const short8* B3 = (const short8*)(wsu + U_B3);
    const short8* B4 = (const short8*)(wsu + U_B4);
    const short8* B5 = (const short8*)(wsu + U_B5);
    const short8* B6 = (const short8*)(wsu + U_B6);

    // ---- hoist ALL weight fragments into registers (t-invariant) ----
    short8 wB1[2];
    #pragma unroll
    for (int i = 0; i < 2; ++i) wB1[i] = B1[(w * 2 + i) * 64 + lane];
    short8 wB24[4];
    #pragma unroll
    for (int ks = 0; ks < 4; ++ks)
        wB24[ks] = (w < 4) ? B2[(w * 4 + ks) * 64 + lane]
                           : B4[((w - 4) * 4 + ks) * 64 + lane];
    short8 wB3[2];
    #pragma unroll
    for (int i = 0; i < 2; ++i) wB3[i] = B3[(((w < 4) ? w : (w - 4)) * 2 + i) * 64 + lane];
    short8 wB5[12], wB6[12];
    #pragma unroll
    for (int tt = 0; tt < 3; ++tt)
        #pragma unroll
        for (int ks = 0; ks < 4; ++ks) {
            wB5[tt * 4 + ks] = B5[((w + tt * 8) * 4 + ks) * 64 + lane];
            wB6[tt * 4 + ks] = B6[((w + tt * 8) * 4 + ks) * 64 + lane];
        }

    // hoisted per-thread bias constants
    const int jH = w * 16 + ln15;
    const float c_bdh = bdh[jH];
    const float c_br  = bih[jH]       + bhh[jH];
    const float c_bz  = bih[jH + 128] + bhh[jH + 128];
    const float c_bin = bih[jH + 256];
    const float c_bhn = bhh[jH + 256];
    const int vC = (w < 4 ? w : w - 4) * 16 + ln15;
    const float c_bh = (vC < VF) ? bh[vC] : 0.f;
    const float c_bf = (vC < VF) ? bf[vC] : 0.f;
    const float c_bc = (vC < VF) ? bc[vC] : 0.f;

    // ---- loader mapping (waves 4-7): row lr in [0,16), col lc + 16k ----
    const int q  = tid & 255;
    const int lr = q >> 4;
    const int lc = q & 15;
    const size_t rowbase = (size_t)(b0 + lr) * (TT * VF);
    const float* px = x + rowbase;
    const float* pm = mask + rowbase;
    const float* pd = deltas + rowbase;
    float wdx4[4], bdx4[4];
    #pragma unroll
    for (int k = 0; k < 4; ++k) {
        int v = lc + 16 * k;
        wdx4[k] = (v < VF) ? ws[WF_DWDX + v] : 0.f;
        bdx4[k] = (v < VF) ? bdx[v] : 0.f;
    }

    float hreg[4] = {0.f, 0.f, 0.f, 0.f};   // holds h_decay(t) at top of step t

    // zero LDS (frag pads must be zero; S_AH=0 == h_decay(0))
    for (int i = tid; i < F_TOT; i += NTH) smf[i] = 0.f;
    __syncthreads();

    if (tid < TT) smf[F_IDT + tid] = ws[WF_INV + tid];
    // t=0 inputs (waves 4-7, same mapping as steady-state commits)
    if (w >= 4) {
        #pragma unroll
        for (int k = 0; k < 4; ++k) {
            int v = lc + 16 * k;
            if (v < VF) {
                float xv = px[v], mv = pm[v], dv = pd[v];
                smf[F_SX + lr * 60 + v] = xv;
                smf[F_SM + lr * 60 + v] = mv;
                ushort mb = f2bf(mv);
                smu[S_AGM  + fragIdx(lr, 59 + v)] = mb;
                smu[S_AIM0 + fragIdx(lr, 59 + v)] = mb;
                float gx = __expf(-fmaxf(fmaf(dv, wdx4[k], bdx4[k]), 0.f));
                smu[S_AGM + fragIdx(lr, v)] = f2bf(gx);
            }
        }
    }
    __syncthreads();

    float loss_acc = 0.f;

    for (int t = 0; t < TT; ++t) {
        // ---- prefetch t+1 inputs (waves 4-7); stays in flight across raw barriers ----
        float pxv[4], pmv[4], pdv[4];
        if (w >= 4 && t + 1 < TT) {
            const size_t toff = (size_t)(t + 1) * VF;
            #pragma unroll
            for (int k = 0; k < 4; ++k) {
                int v = lc + 16 * k;
                if (v < VF) { pxv[k] = px[toff + v]; pmv[k] = pm[toff + v]; pdv[k] = pd[toff + v]; }
            }
        }

        // ---- Phase A: x_h | beta GEMMs; all waves gh GEMM ----
        short8 ah[4];
        #pragma unroll
        for (int ks = 0; ks < 4; ++ks)
            ah[ks] = *(const short8*)(smu + S_AH + (ks * 64 + lane) * 8);
        f32x4 gHa[3];
        #pragma unroll
        for (int tt = 0; tt < 3; ++tt) gHa[tt] = (f32x4){0.f, 0.f, 0.f, 0.f};
        float xh[4], mmv[4];
        if (w < 4) {
            f32x4 acc = {0.f, 0.f, 0.f, 0.f};
            #pragma unroll
            for (int ks = 0; ks < 4; ++ks) acc = MFMA(ah[ks], wB24[ks], acc);
            #pragma unroll
            for (int tt = 0; tt < 3; ++tt)
                #pragma unroll
                for (int ks = 0; ks < 4; ++ks) gHa[tt] = MFMA(ah[ks], wB6[tt * 4 + ks], gHa[tt]);
            if (vC < VF) {
                #pragma unroll
                for (int i = 0; i < 4; ++i) {
                    int m = quad * 4 + i;
                    xh[i] = acc[i] + c_bh;               // kept in regs for B
                    float mm = smf[F_SM + m * 60 + vC];
                    mmv[i] = mm;
                    float xr = fmaf(mm, smf[F_SX + m * 60 + vC], (1.f - mm) * xh[i]);
                    smu[S_AXR + fragIdx(m, vC)] = f2bf(xr);
                }
            }
        } else {
            short8 ag[4];
            #pragma unroll
            for (int ks = 0; ks < 4; ++ks)
                ag[ks] = *(const short8*)(smu + S_AGM + (ks * 64 + lane) * 8);
            f32x4 acc = {0.f, 0.f, 0.f, 0.f};
            #pragma unroll
            for (int ks = 0; ks < 4; ++ks) acc = MFMA(ag[ks], wB24[ks], acc);
            #pragma unroll
            for (int tt = 0; tt < 3; ++tt)
                #pragma unroll
                for (int ks = 0; ks < 4; ++ks) gHa[tt] = MFMA(ah[ks], wB6[tt * 4 + ks], gHa[tt]);
            if (vC < VF) {
                #pragma unroll
                for (int i = 0; i < 4; ++i) {
                    int m = quad * 4 + i;
                    smf[F_SB + betaIdx(m, vC)] = acc[i] + c_bc;
                }
            }
        }
        block_sync();

        // ---- Phase B: xu GEMM + combine/loss/x_imp | commit d(t+1) ----
        if (w < 4) {
            short8 a0 = *(const short8*)(smu + S_AXR + (0 * 64 + lane) * 8);
            short8 a1 = *(const short8*)(smu + S_AXR + (1 * 64 + lane) * 8);
            f32x4 acc = {0.f, 0.f, 0.f, 0.f};
            acc = MFMA(a0, wB3[0], acc);
            acc = MFMA(a1, wB3[1], acc);
            if (vC < VF) {
                const float idt = smf[F_IDT + t];
                const int aimW = S_AIM0 + (t & 1) * 2048;
                #pragma unroll
                for (int i = 0; i < 4; ++i) {
                    int m = quad * 4 + i;
                    float xu   = acc[i] + c_bf;          // Wf diag zeroed at pack time
                    float beta = smf[F_SB + betaIdx(m, vC)];
                    float xc   = beta * xu + (1.f - beta) * xh[i];
                    float mm   = mmv[i];
                    float xv   = smf[F_SX + m * 60 + vC];
                    loss_acc += fabsf(xv - xc) * mm * idt;
                    float xi = fmaf(mm, xv, (1.f - mm) * xc);
                    out[(size_t)(b0 + m) * (TT * VF) + (size_t)t * VF + vC] = xi;
                    smu[aimW + fragIdx(m, vC)] = f2bf(xi);
                }
            }
        } else if (t + 1 < TT) {
            // commit d(t+1): raw bf16 for the gamma_h GEMM + elementwise gamma_x
            #pragma unroll
            for (int k = 0; k < 4; ++k) {
                int v = lc + 16 * k;
                if (v < VF) {
                    smu[S_AD + fragIdx(lr, v)] = f2bf(pdv[k]);
                    float gx = __expf(-fmaxf(fmaf(pdv[k], wdx4[k], bdx4[k]), 0.f));
                    smu[S_AGM + fragIdx(lr, v)] = f2bf(gx);
                }
            }
        }
        block_sync();

        // ---- Phase C: gi GEMM + gamma(t+1) GEMM + gates + h_decay(t+1) ----
        {
            const int aimR = S_AIM0 + (t & 1) * 2048;
            short8 ai[4];
            #pragma unroll
            for (int ks = 0; ks < 4; ++ks)
                ai[ks] = *(const short8*)(smu + aimR + (ks * 64 + lane) * 8);
            f32x4 gI[3];
            #pragma unroll
            for (int tt = 0; tt < 3; ++tt) gI[tt] = (f32x4){0.f, 0.f, 0.f, 0.f};
            #pragma unroll
            for (int tt = 0; tt < 3; ++tt)
                #pragma unroll
                for (int ks = 0; ks < 4; ++ks) gI[tt] = MFMA(ai[ks], wB5[tt * 4 + ks], gI[tt]);
            float gdec[4] = {0.f, 0.f, 0.f, 0.f};
            if (t + 1 < TT) {
                short8 d0 = *(const short8*)(smu + S_AD + (0 * 64 + lane) * 8);
                short8 d1 = *(const short8*)(smu + S_AD + (1 * 64 + lane) * 8);
                f32x4 gacc = {0.f, 0.f, 0.f, 0.f};
                gacc = MFMA(d0, wB1[0], gacc);
                gacc = MFMA(d1, wB1[1], gacc);
                #pragma unroll
                for (int i = 0; i < 4; ++i)
                    gdec[i] = __expf(-fmaxf(gacc[i] + c_bdh, 0.f));
            }
            #pragma unroll
            for (int i = 0; i < 4; ++i) {
                int m = quad * 4 + i;
                float r_ = sigm(gI[0][i] + gHa[0][i] + c_br);
                float z_ = sigm(gI[1][i] + gHa[1][i] + c_bz);
                float hn = gHa[2][i] + c_bhn;
                float n_ = tanh_f(fmaf(r_, hn, gI[2][i] + c_bin));
                float hnew = fmaf(z_, hreg[i] - n_, n_);
                out[OFF_HID + (size_t)(b0 + m) * (TT * HF) + (size_t)t * HF + jH] = hnew;
                float hd = hnew * gdec[i];               // h_decay(t+1)
                hreg[i] = hd;
                if (t + 1 < TT) smu[S_AH + fragIdx(m, jH)] = f2bf(hd);
            }
        }
        // C tail: waves 4-7 commit x/m(t+1)
        if (w >= 4 && t + 1 < TT) {
            const int aimN = S_AIM0 + ((t + 1) & 1) * 2048;
            #pragma unroll
            for (int k = 0; k < 4; ++k) {
                int v = lc + 16 * k;
                if (v < VF) {
                    smf[F_SX + lr * 60 + v] = pxv[k];
                    smf[F_SM + lr * 60 + v] = pmv[k];
                    ushort mb = f2bf(pmv[k]);
                    smu[S_AGM + fragIdx(lr, 59 + v)] = mb;
                    smu[aimN  + fragIdx(lr, 59 + v)] = mb;
                }
            }
        }
        block_sync();
    }

    // ---- loss reduction ----
    __syncthreads();
    float vsum = loss_acc;
    for (int off = 32; off > 0; off >>= 1) vsum += __shfl_down(vsum, off);
    if (lane == 0) smf[F_RED + w] = vsum;
    __syncthreads();
    if (tid == 0) {
        float s = 0.f;
        #pragma unroll
        for (int i = 0; i < 8; ++i) s += smf[F_RED + i];
        atomicAdd(out + LOSS_IDX, s);
    }
}

extern "C" void kernel_launch(void* const* d_in, const int* in_sizes, int n_in,
                              void* d_out, int out_size, void* d_ws, size_t ws_size,
                              hipStream_t stream) {
    const float* x      = (const float*)d_in[0];
    const float* mask   = (const float*)d_in[1];
    const float* deltas = (const float*)d_in[2];
    const float* Wdh    = (const float*)d_in[3];
    const float* bdh    = (const float*)d_in[4];
    const float* Wdx    = (const float*)d_in[5];
    const float* bdx    = (const float*)d_in[6];
    const float* Wh     = (const float*)d_in[7];
    const float* bh     = (const float*)d_in[8];
    const float* Wf     = (const float*)d_in[9];
    const float* bf     = (const float*)d_in[10];
    const float* Wc     = (const float*)d_in[11];
    const float* bc     = (const float*)d_in[12];
    const float* Wih    = (const float*)d_in[13];
    const float* Whh    = (const float*)d_in[14];
    const float* bih    = (const float*)d_in[15];
    const float* bhh    = (const float*)d_in[16];
    float* out = (float*)d_out;
    float* ws  = (float*)d_ws;

    prep_zero<<<1, 128, 0, stream>>>(ws, out + LOSS_IDX);
    prep_acc<<<(BB * TT) / PA_R, 256, 0, stream>>>(mask, ws);
    prep_pack<<<65, 256, 0, stream>>>(Wdh, Wdx, Wh, Wf, Wc, Wih, Whh, ws);
    rits_main<<<NBLK, NTH, 0, stream>>>(x, mask, deltas, bdh, bdx, bh, bf, bc,
                                        bih, bhh, ws, out);
}